// Round 1
// baseline (845.602 us; speedup 1.0000x reference)
//
#include <hip/hip_runtime.h>
#include <math.h>

#define B_ 16
#define L_ 8192
#define C_ 256
#define KTOP 2457            // max(1, int(8192*0.3))
#define JT 20                // recurrence taps; ||A||^20 ~ 1e-16 -> exact to fp32
#define M1 (B_*L_)           // 131072
#define M2 (B_*KTOP)         // 39312

// workspace layout in floats
#define XP_OFF  ((size_t)0)
#define Y_OFF   (XP_OFF + (size_t)M1*C_)        // 33554432
#define E_OFF   (Y_OFF  + (size_t)M2*C_)        // 43618304
#define CN_OFF  (E_OFF  + (size_t)M1)           // 43749376
#define CF_OFF  (CN_OFF + (size_t)B_*C_)        // 43753472
#define IDX_OFF (CF_OFF + (size_t)JT*C_)        // 43758592 (ints)

// ---------------- coef: coef[j][c] = sigmoid(Cp[c,:]) . (A^j sigmoid(Bp)) ----------------
__global__ void coef_kernel(const float* __restrict__ A, const float* __restrict__ Bp,
                            const float* __restrict__ Cp, float* __restrict__ cf)
{
    int c = threadIdx.x;                       // 256 threads
    __shared__ float As[256];
    __shared__ float v0[16];
    As[c] = A[c];
    if (c < 16) v0[c] = 1.0f / (1.0f + expf(-Bp[c]));
    float sC[16];
    #pragma unroll
    for (int i = 0; i < 16; i++) sC[i] = 1.0f / (1.0f + expf(-Cp[c*16 + i]));
    __syncthreads();
    float v[16];
    #pragma unroll
    for (int i = 0; i < 16; i++) v[i] = v0[i];
    for (int j = 0; j < JT; j++) {
        float d = 0.f;
        #pragma unroll
        for (int i = 0; i < 16; i++) d += sC[i] * v[i];
        cf[j*C_ + c] = d;
        float nv[16];
        #pragma unroll
        for (int i = 0; i < 16; i++) {
            float s = 0.f;
            #pragma unroll
            for (int m = 0; m < 16; m++) s += As[i*16 + m] * v[m];
            nv[i] = s;
        }
        #pragma unroll
        for (int i = 0; i < 16; i++) v[i] = nv[i];
    }
}

// ---------------- GEMM1: xp[m,n] = sum_k dyt(x[m,k]) * Wi[n,k] + bi[n] ----------------
// BM=64, BN=256, BK=32, 256 threads, 8x8 micro-tile
__global__ __launch_bounds__(256) void gemm1_kernel(
    const float* __restrict__ x, const float* __restrict__ Wi,
    const float* __restrict__ bi, const float* __restrict__ alpha,
    const float* __restrict__ dw, const float* __restrict__ db,
    float* __restrict__ xp)
{
    __shared__ float As[32][64];
    __shared__ float Bs[32][256];
    const int tid = threadIdx.x;
    const int tm = tid >> 5, tn = tid & 31;
    const int row0 = blockIdx.x * 64;
    const int lkq = (tid & 7) * 4;
    const int lm  = tid >> 3;                  // 0..31
    const float al = alpha[0];

    float acc[8][8];
    #pragma unroll
    for (int i = 0; i < 8; i++)
        #pragma unroll
        for (int j = 0; j < 8; j++) acc[i][j] = 0.f;

    for (int k0 = 0; k0 < C_; k0 += 32) {
        float4 w4 = *(const float4*)&dw[k0 + lkq];
        float4 b4 = *(const float4*)&db[k0 + lkq];
        #pragma unroll
        for (int r = 0; r < 2; r++) {
            int m = lm + r*32;
            float4 v = *(const float4*)&x[(size_t)(row0 + m)*C_ + k0 + lkq];
            As[lkq+0][m] = tanhf(al*v.x)*w4.x + b4.x;
            As[lkq+1][m] = tanhf(al*v.y)*w4.y + b4.y;
            As[lkq+2][m] = tanhf(al*v.z)*w4.z + b4.z;
            As[lkq+3][m] = tanhf(al*v.w)*w4.w + b4.w;
        }
        #pragma unroll
        for (int r = 0; r < 8; r++) {
            int n = lm + r*32;
            float4 v = *(const float4*)&Wi[(size_t)n*C_ + k0 + lkq];
            Bs[lkq+0][n] = v.x; Bs[lkq+1][n] = v.y;
            Bs[lkq+2][n] = v.z; Bs[lkq+3][n] = v.w;
        }
        __syncthreads();
        #pragma unroll
        for (int kk = 0; kk < 32; kk++) {
            float a[8], bb[8];
            *(float4*)&a[0] = *(const float4*)&As[kk][tm*4];
            *(float4*)&a[4] = *(const float4*)&As[kk][tm*4 + 32];
            *(float4*)&bb[0] = *(const float4*)&Bs[kk][tn*4];
            *(float4*)&bb[4] = *(const float4*)&Bs[kk][tn*4 + 128];
            #pragma unroll
            for (int i = 0; i < 8; i++)
                #pragma unroll
                for (int j = 0; j < 8; j++)
                    acc[i][j] = fmaf(a[i], bb[j], acc[i][j]);
        }
        __syncthreads();
    }
    float4 bi0 = *(const float4*)&bi[tn*4];
    float4 bi1 = *(const float4*)&bi[tn*4 + 128];
    #pragma unroll
    for (int i = 0; i < 8; i++) {
        int row = row0 + ((i < 4) ? (tm*4 + i) : (32 + tm*4 + (i-4)));
        float4 o0 = make_float4(acc[i][0]+bi0.x, acc[i][1]+bi0.y, acc[i][2]+bi0.z, acc[i][3]+bi0.w);
        float4 o1 = make_float4(acc[i][4]+bi1.x, acc[i][5]+bi1.y, acc[i][6]+bi1.z, acc[i][7]+bi1.w);
        *(float4*)&xp[(size_t)row*C_ + tn*4] = o0;
        *(float4*)&xp[(size_t)row*C_ + tn*4 + 128] = o1;
    }
}

// ---------------- center: cn[b,:] = normalize(xp[b, L/2, :]) ----------------
__global__ void center_kernel(const float* __restrict__ xp, float* __restrict__ cn)
{
    int b = blockIdx.x, lane = threadIdx.x;    // 64 threads
    float4 v = ((const float4*)(xp + ((size_t)b*L_ + L_/2)*C_))[lane];
    float ss = v.x*v.x + v.y*v.y + v.z*v.z + v.w*v.w;
    #pragma unroll
    for (int off = 32; off; off >>= 1) ss += __shfl_xor(ss, off);
    float inv = 1.0f / fmaxf(sqrtf(ss), 1e-12f);
    ((float4*)(cn + b*C_))[lane] = make_float4(v.x*inv, v.y*inv, v.z*inv, v.w*inv);
}

// ---------------- e[m] = dot(xp[m,:], cn[b,:]) / max(||xp[m,:]||, eps) ----------------
__global__ __launch_bounds__(256) void e_kernel(const float* __restrict__ xp,
    const float* __restrict__ cn, float* __restrict__ e)
{
    int tid = threadIdx.x, wid = tid >> 6, lane = tid & 63;
    size_t m = (size_t)blockIdx.x * 4 + wid;
    int b = (int)(m >> 13);
    float4 v  = ((const float4*)(xp + m*C_))[lane];
    float4 c4 = ((const float4*)(cn + (size_t)b*C_))[lane];
    float ss = v.x*v.x + v.y*v.y + v.z*v.z + v.w*v.w;
    float dt = v.x*c4.x + v.y*c4.y + v.z*c4.z + v.w*c4.w;
    #pragma unroll
    for (int off = 32; off; off >>= 1) { ss += __shfl_xor(ss, off); dt += __shfl_xor(dt, off); }
    if (lane == 0) e[m] = dt / fmaxf(sqrtf(ss), 1e-12f);
}

// ---------------- softmax over L per batch + bitonic sort (desc, idx-asc ties) ----------------
__global__ __launch_bounds__(1024) void softsort_kernel(
    const float* __restrict__ e, float* __restrict__ sim, int* __restrict__ idxo)
{
    __shared__ unsigned long long keys[L_];    // 64KB
    float* scratch = (float*)keys;
    const int b = blockIdx.x, tid = threadIdx.x;
    const int lane = tid & 63, wid = tid >> 6; // 16 waves
    const float* eb = e + (size_t)b*L_;
    float ev[8];
    #pragma unroll
    for (int s = 0; s < 8; s++) ev[s] = eb[tid + s*1024];
    float mx = ev[0];
    #pragma unroll
    for (int s = 1; s < 8; s++) mx = fmaxf(mx, ev[s]);
    #pragma unroll
    for (int off = 32; off; off >>= 1) mx = fmaxf(mx, __shfl_xor(mx, off));
    if (lane == 0) scratch[wid] = mx;
    __syncthreads();
    if (tid == 0) {
        float m2 = scratch[0];
        for (int i = 1; i < 16; i++) m2 = fmaxf(m2, scratch[i]);
        scratch[20] = m2;
    }
    __syncthreads();
    mx = scratch[20];
    float pv[8], sum = 0.f;
    #pragma unroll
    for (int s = 0; s < 8; s++) { pv[s] = expf(ev[s] - mx); sum += pv[s]; }
    #pragma unroll
    for (int off = 32; off; off >>= 1) sum += __shfl_xor(sum, off);
    __syncthreads();
    if (lane == 0) scratch[wid] = sum;
    __syncthreads();
    if (tid == 0) {
        float s2 = 0.f;
        for (int i = 0; i < 16; i++) s2 += scratch[i];
        scratch[21] = s2;
    }
    __syncthreads();
    float inv = 1.0f / scratch[21];
    __syncthreads();                           // everyone read scratch before keys overwrite
    #pragma unroll
    for (int s = 0; s < 8; s++) {
        int l = tid + s*1024;
        float sm = pv[s] * inv;
        sim[(size_t)b*L_ + l] = sm;
        keys[l] = ((unsigned long long)__float_as_uint(sm) << 32) | (unsigned)(0xFFFFFFFFu - l);
    }
    __syncthreads();
    for (int ksz = 2; ksz <= L_; ksz <<= 1) {
        for (int j = ksz >> 1; j > 0; j >>= 1) {
            #pragma unroll
            for (int s = 0; s < 8; s++) {
                int i = tid + s*1024;
                int ixj = i ^ j;
                if (ixj > i) {
                    unsigned long long a = keys[i], c = keys[ixj];
                    bool desc = ((i & ksz) == 0);
                    bool sw = desc ? (a < c) : (a > c);
                    if (sw) { keys[i] = c; keys[ixj] = a; }
                }
            }
            __syncthreads();
        }
    }
    for (int t = tid; t < KTOP; t += 1024)
        idxo[b*KTOP + t] = (int)(0xFFFFFFFFu - (unsigned)(keys[t] & 0xFFFFFFFFu));
}

// ---------------- y[m,c] = conv_w[c] * sum_j cf[j][c] * xp[b, idx[t-j], c] ----------------
__global__ void y_kernel(const float* __restrict__ xp, const int* __restrict__ idx,
    const float* __restrict__ conv_w, const float* __restrict__ cf, float* __restrict__ y)
{
    int m = blockIdx.x;                        // 0..M2-1
    int lane = threadIdx.x;                    // 64
    int b = m / KTOP, t = m - b*KTOP;
    const int* idxb = idx + b*KTOP;
    float4 acc = make_float4(0.f, 0.f, 0.f, 0.f);
    int jmax = (t < JT-1) ? t : (JT-1);
    for (int j = 0; j <= jmax; j++) {
        int l = idxb[t - j];
        float4 v  = ((const float4*)(xp + ((size_t)b*L_ + l)*C_))[lane];
        float4 c4 = ((const float4*)(cf + (size_t)j*C_))[lane];
        acc.x += v.x*c4.x; acc.y += v.y*c4.y; acc.z += v.z*c4.z; acc.w += v.w*c4.w;
    }
    float4 cw = ((const float4*)conv_w)[lane];
    acc.x *= cw.x; acc.y *= cw.y; acc.z *= cw.z; acc.w *= cw.w;
    ((float4*)(y + (size_t)m*C_))[lane] = acc;
}

// ---------------- residual copy ----------------
__global__ void copy_kernel(const float4* __restrict__ src, float4* __restrict__ dst)
{
    size_t n4 = (size_t)M1*C_/4;
    for (size_t i = (size_t)blockIdx.x*blockDim.x + threadIdx.x; i < n4;
         i += (size_t)gridDim.x*blockDim.x)
        dst[i] = src[i];
}

// ---------------- GEMM2 + scatter epilogue: out[b,l,:] = x[b,l,:] + y@Wo.T + bo ----------------
__global__ __launch_bounds__(256) void gemm2_kernel(
    const float* __restrict__ y, const float* __restrict__ Wo,
    const float* __restrict__ bo, const float* __restrict__ x,
    const int* __restrict__ idx, float* __restrict__ out0)
{
    __shared__ float As[32][64];
    __shared__ float Bs[32][256];
    const int tid = threadIdx.x;
    const int tm = tid >> 5, tn = tid & 31;
    const int row0 = blockIdx.x * 64;
    const int lkq = (tid & 7) * 4;
    const int lm  = tid >> 3;

    float acc[8][8];
    #pragma unroll
    for (int i = 0; i < 8; i++)
        #pragma unroll
        for (int j = 0; j < 8; j++) acc[i][j] = 0.f;

    for (int k0 = 0; k0 < C_; k0 += 32) {
        #pragma unroll
        for (int r = 0; r < 2; r++) {
            int m = row0 + lm + r*32;
            float4 v = (m < M2) ? *(const float4*)&y[(size_t)m*C_ + k0 + lkq]
                                : make_float4(0.f, 0.f, 0.f, 0.f);
            As[lkq+0][lm + r*32] = v.x; As[lkq+1][lm + r*32] = v.y;
            As[lkq+2][lm + r*32] = v.z; As[lkq+3][lm + r*32] = v.w;
        }
        #pragma unroll
        for (int r = 0; r < 8; r++) {
            int n = lm + r*32;
            float4 v = *(const float4*)&Wo[(size_t)n*C_ + k0 + lkq];
            Bs[lkq+0][n] = v.x; Bs[lkq+1][n] = v.y;
            Bs[lkq+2][n] = v.z; Bs[lkq+3][n] = v.w;
        }
        __syncthreads();
        #pragma unroll
        for (int kk = 0; kk < 32; kk++) {
            float a[8], bb[8];
            *(float4*)&a[0] = *(const float4*)&As[kk][tm*4];
            *(float4*)&a[4] = *(const float4*)&As[kk][tm*4 + 32];
            *(float4*)&bb[0] = *(const float4*)&Bs[kk][tn*4];
            *(float4*)&bb[4] = *(const float4*)&Bs[kk][tn*4 + 128];
            #pragma unroll
            for (int i = 0; i < 8; i++)
                #pragma unroll
                for (int j = 0; j < 8; j++)
                    acc[i][j] = fmaf(a[i], bb[j], acc[i][j]);
        }
        __syncthreads();
    }
    float4 bo0 = *(const float4*)&bo[tn*4];
    float4 bo1 = *(const float4*)&bo[tn*4 + 128];
    #pragma unroll
    for (int i = 0; i < 8; i++) {
        int m = row0 + ((i < 4) ? (tm*4 + i) : (32 + tm*4 + (i-4)));
        if (m < M2) {
            int b = m / KTOP, t = m - b*KTOP;
            int l = idx[b*KTOP + t];
            size_t base = ((size_t)b*L_ + l)*C_;
            float4 x0 = *(const float4*)&x[base + tn*4];
            float4 x1 = *(const float4*)&x[base + tn*4 + 128];
            float4 o0 = make_float4(acc[i][0]+bo0.x+x0.x, acc[i][1]+bo0.y+x0.y,
                                    acc[i][2]+bo0.z+x0.z, acc[i][3]+bo0.w+x0.w);
            float4 o1 = make_float4(acc[i][4]+bo1.x+x1.x, acc[i][5]+bo1.y+x1.y,
                                    acc[i][6]+bo1.z+x1.z, acc[i][7]+bo1.w+x1.w);
            *(float4*)&out0[base + tn*4] = o0;
            *(float4*)&out0[base + tn*4 + 128] = o1;
        }
    }
}

extern "C" void kernel_launch(void* const* d_in, const int* in_sizes, int n_in,
                              void* d_out, int out_size, void* d_ws, size_t ws_size,
                              hipStream_t stream)
{
    const float* x      = (const float*)d_in[0];
    const float* alpha  = (const float*)d_in[1];
    const float* dyt_w  = (const float*)d_in[2];
    const float* dyt_b  = (const float*)d_in[3];
    const float* Wi     = (const float*)d_in[4];
    const float* bi     = (const float*)d_in[5];
    const float* conv_w = (const float*)d_in[6];
    const float* A      = (const float*)d_in[7];
    const float* Bp     = (const float*)d_in[8];
    const float* Cp     = (const float*)d_in[9];
    const float* Wo     = (const float*)d_in[10];
    const float* bo     = (const float*)d_in[11];

    float* ws  = (float*)d_ws;
    float* xp  = ws + XP_OFF;
    float* yb  = ws + Y_OFF;
    float* e   = ws + E_OFF;
    float* cn  = ws + CN_OFF;
    float* cf  = ws + CF_OFF;
    int*   idx = (int*)(ws + IDX_OFF);

    float* out0 = (float*)d_out;
    float* sim  = out0 + (size_t)M1*C_;

    coef_kernel<<<1, 256, 0, stream>>>(A, Bp, Cp, cf);
    gemm1_kernel<<<M1/64, 256, 0, stream>>>(x, Wi, bi, alpha, dyt_w, dyt_b, xp);
    center_kernel<<<B_, 64, 0, stream>>>(xp, cn);
    e_kernel<<<M1/4, 256, 0, stream>>>(xp, cn, e);
    softsort_kernel<<<B_, 1024, 0, stream>>>(e, sim, idx);
    y_kernel<<<M2, 64, 0, stream>>>(xp, idx, conv_w, cf, yb);
    copy_kernel<<<2048, 256, 0, stream>>>((const float4*)x, (float4*)out0);
    gemm2_kernel<<<(M2 + 63)/64, 256, 0, stream>>>(yb, Wo, bo, x, idx, out0);
}

// Round 2
// 740.163 us; speedup vs baseline: 1.1425x; 1.1425x over previous
//
#include <hip/hip_runtime.h>
#include <math.h>

#define B_ 16
#define L_ 8192
#define C_ 256
#define KTOP 2457            // max(1, int(8192*0.3))
#define JT 20                // recurrence taps; ||A||^20 ~ 1e-16 -> exact at fp32
#define M1 (B_*L_)           // 131072
#define M2 (B_*KTOP)         // 39312

// workspace layout in floats
#define XP_OFF  ((size_t)0)
#define Y_OFF   (XP_OFF + (size_t)M1*C_)        // 33554432
#define E_OFF   (Y_OFF  + (size_t)M2*C_)        // 43618304
#define CN_OFF  (E_OFF  + (size_t)M1)           // 43749376
#define CF_OFF  (CN_OFF + (size_t)B_*C_)        // 43753472
#define IDX_OFF (CF_OFF + (size_t)JT*C_)        // 43758592 (ints)
#define WIT_OFF (IDX_OFF + (size_t)M2)          // 43797904
#define WOT_OFF (WIT_OFF + (size_t)C_*C_)       // 43863440

// ---------------- transpose Wi/Wo (256x256 each) into [K][N] layout ----------------
__global__ void transpose_kernel(const float* __restrict__ Wi, const float* __restrict__ Wo,
                                 float* __restrict__ WiT, float* __restrict__ WoT)
{
    __shared__ float t[32][33];
    const float* src = blockIdx.z ? Wo : Wi;
    float* dst = blockIdx.z ? WoT : WiT;
    int r0 = blockIdx.y * 32, c0 = blockIdx.x * 32;
    int tx = threadIdx.x, ty = threadIdx.y;      // 32 x 8
    #pragma unroll
    for (int r = 0; r < 4; r++)
        t[ty + r*8][tx] = src[(size_t)(r0 + ty + r*8)*C_ + c0 + tx];
    __syncthreads();
    #pragma unroll
    for (int r = 0; r < 4; r++)
        dst[(size_t)(c0 + ty + r*8)*C_ + r0 + tx] = t[tx][ty + r*8];
}

// ---------------- coef: cf[j][c] = sigmoid(Cp[c,:]) . (A^j sigmoid(Bp)) ----------------
__global__ void coef_kernel(const float* __restrict__ A, const float* __restrict__ Bp,
                            const float* __restrict__ Cp, float* __restrict__ cf)
{
    int c = threadIdx.x;                       // 256 threads
    __shared__ float As[256];
    __shared__ float v0[16];
    As[c] = A[c];
    if (c < 16) v0[c] = 1.0f / (1.0f + expf(-Bp[c]));
    float sC[16];
    #pragma unroll
    for (int i = 0; i < 16; i++) sC[i] = 1.0f / (1.0f + expf(-Cp[c*16 + i]));
    __syncthreads();
    float v[16];
    #pragma unroll
    for (int i = 0; i < 16; i++) v[i] = v0[i];
    for (int j = 0; j < JT; j++) {
        float d = 0.f;
        #pragma unroll
        for (int i = 0; i < 16; i++) d += sC[i] * v[i];
        cf[j*C_ + c] = d;
        float nv[16];
        #pragma unroll
        for (int i = 0; i < 16; i++) {
            float s = 0.f;
            #pragma unroll
            for (int m = 0; m < 16; m++) s += As[i*16 + m] * v[m];
            nv[i] = s;
        }
        #pragma unroll
        for (int i = 0; i < 16; i++) v[i] = nv[i];
    }
}

// ---------------- GEMM1: xp[m,n] = sum_k dyt(x[m,k]) * Wi[n,k] + bi[n] ----------------
// BM=128, BN=256(full), BK=32, 256 threads, 16x8 micro-tile
__global__ __launch_bounds__(256, 2) void gemm1_kernel(
    const float* __restrict__ x, const float* __restrict__ WiT,
    const float* __restrict__ bi, const float* __restrict__ alpha,
    const float* __restrict__ dw, const float* __restrict__ db,
    float* __restrict__ xp)
{
    __shared__ float As[32*132];   // [kk][m], stride 132 keeps 16B align, 4-way wr conflicts
    __shared__ float Bs[32*256];   // [kk][n], row-copy staging: conflict-free
    const int tid = threadIdx.x;
    const int tn2 = tid & 31;      // owns cols tn2*8 .. +8
    const int tm2 = tid >> 5;      // owns rows tm2*16 .. +16
    const int m0 = blockIdx.x * 128;
    const float al = alpha[0];

    float acc[16][8];
    #pragma unroll
    for (int i = 0; i < 16; i++)
        #pragma unroll
        for (int j = 0; j < 8; j++) acc[i][j] = 0.f;

    for (int k0 = 0; k0 < C_; k0 += 32) {
        // A stage: 128x32 tile, dyt transform, transpose into As[kk][m]
        #pragma unroll
        for (int it = 0; it < 4; it++) {
            int idx = tid + it*256;
            int ar = idx >> 3;             // m-local 0..127
            int ak = (idx & 7) * 4;        // k-local 0,4,..,28
            float4 v  = *(const float4*)&x[(size_t)(m0 + ar)*C_ + k0 + ak];
            float4 w4 = *(const float4*)&dw[k0 + ak];
            float4 b4 = *(const float4*)&db[k0 + ak];
            As[(ak+0)*132 + ar] = tanhf(al*v.x)*w4.x + b4.x;
            As[(ak+1)*132 + ar] = tanhf(al*v.y)*w4.y + b4.y;
            As[(ak+2)*132 + ar] = tanhf(al*v.z)*w4.z + b4.z;
            As[(ak+3)*132 + ar] = tanhf(al*v.w)*w4.w + b4.w;
        }
        // B stage: row copy of WiT rows k0..k0+32 (conflict-free)
        #pragma unroll
        for (int it = 0; it < 8; it++) {
            int idx = tid + it*256;
            int br = idx >> 6;             // 0..31
            int bc = (idx & 63) * 4;
            *(float4*)&Bs[br*256 + bc] = *(const float4*)&WiT[(size_t)(k0 + br)*C_ + bc];
        }
        __syncthreads();
        #pragma unroll 2
        for (int kk = 0; kk < 32; kk++) {
            float a[16], b[8];
            *(float4*)&a[0]  = *(const float4*)&As[kk*132 + tm2*16];
            *(float4*)&a[4]  = *(const float4*)&As[kk*132 + tm2*16 + 4];
            *(float4*)&a[8]  = *(const float4*)&As[kk*132 + tm2*16 + 8];
            *(float4*)&a[12] = *(const float4*)&As[kk*132 + tm2*16 + 12];
            *(float4*)&b[0]  = *(const float4*)&Bs[kk*256 + tn2*8];
            *(float4*)&b[4]  = *(const float4*)&Bs[kk*256 + tn2*8 + 4];
            #pragma unroll
            for (int i = 0; i < 16; i++)
                #pragma unroll
                for (int j = 0; j < 8; j++)
                    acc[i][j] = fmaf(a[i], b[j], acc[i][j]);
        }
        __syncthreads();
    }
    float4 bi0 = *(const float4*)&bi[tn2*8];
    float4 bi1 = *(const float4*)&bi[tn2*8 + 4];
    #pragma unroll
    for (int i = 0; i < 16; i++) {
        size_t row = m0 + tm2*16 + i;
        float4 o0 = make_float4(acc[i][0]+bi0.x, acc[i][1]+bi0.y, acc[i][2]+bi0.z, acc[i][3]+bi0.w);
        float4 o1 = make_float4(acc[i][4]+bi1.x, acc[i][5]+bi1.y, acc[i][6]+bi1.z, acc[i][7]+bi1.w);
        *(float4*)&xp[row*C_ + tn2*8]     = o0;
        *(float4*)&xp[row*C_ + tn2*8 + 4] = o1;
    }
}

// ---------------- center: cn[b,:] = normalize(xp[b, L/2, :]) ----------------
__global__ void center_kernel(const float* __restrict__ xp, float* __restrict__ cn)
{
    int b = blockIdx.x, lane = threadIdx.x;    // 64 threads
    float4 v = ((const float4*)(xp + ((size_t)b*L_ + L_/2)*C_))[lane];
    float ss = v.x*v.x + v.y*v.y + v.z*v.z + v.w*v.w;
    #pragma unroll
    for (int off = 32; off; off >>= 1) ss += __shfl_xor(ss, off);
    float inv = 1.0f / fmaxf(sqrtf(ss), 1e-12f);
    ((float4*)(cn + b*C_))[lane] = make_float4(v.x*inv, v.y*inv, v.z*inv, v.w*inv);
}

// ---------------- e[m] = dot(xp[m,:], cn[b,:]) / max(||xp[m,:]||, eps) ----------------
__global__ __launch_bounds__(256) void e_kernel(const float* __restrict__ xp,
    const float* __restrict__ cn, float* __restrict__ e)
{
    int tid = threadIdx.x, wid = tid >> 6, lane = tid & 63;
    size_t m = (size_t)blockIdx.x * 4 + wid;
    int b = (int)(m >> 13);
    float4 v  = ((const float4*)(xp + m*C_))[lane];
    float4 c4 = ((const float4*)(cn + (size_t)b*C_))[lane];
    float ss = v.x*v.x + v.y*v.y + v.z*v.z + v.w*v.w;
    float dt = v.x*c4.x + v.y*c4.y + v.z*c4.z + v.w*c4.w;
    #pragma unroll
    for (int off = 32; off; off >>= 1) { ss += __shfl_xor(ss, off); dt += __shfl_xor(dt, off); }
    if (lane == 0) e[m] = dt / fmaxf(sqrtf(ss), 1e-12f);
}

// ---------------- softmax over L per batch + bitonic sort (desc, idx-asc ties) ----------------
__global__ __launch_bounds__(1024) void softsort_kernel(
    const float* __restrict__ e, float* __restrict__ sim, int* __restrict__ idxo)
{
    __shared__ unsigned long long keys[L_];    // 64KB
    float* scratch = (float*)keys;
    const int b = blockIdx.x, tid = threadIdx.x;
    const int lane = tid & 63, wid = tid >> 6; // 16 waves
    const float* eb = e + (size_t)b*L_;
    float ev[8];
    #pragma unroll
    for (int s = 0; s < 8; s++) ev[s] = eb[tid + s*1024];
    float mx = ev[0];
    #pragma unroll
    for (int s = 1; s < 8; s++) mx = fmaxf(mx, ev[s]);
    #pragma unroll
    for (int off = 32; off; off >>= 1) mx = fmaxf(mx, __shfl_xor(mx, off));
    if (lane == 0) scratch[wid] = mx;
    __syncthreads();
    if (tid == 0) {
        float m2 = scratch[0];
        for (int i = 1; i < 16; i++) m2 = fmaxf(m2, scratch[i]);
        scratch[20] = m2;
    }
    __syncthreads();
    mx = scratch[20];
    float pv[8], sum = 0.f;
    #pragma unroll
    for (int s = 0; s < 8; s++) { pv[s] = expf(ev[s] - mx); sum += pv[s]; }
    #pragma unroll
    for (int off = 32; off; off >>= 1) sum += __shfl_xor(sum, off);
    __syncthreads();
    if (lane == 0) scratch[wid] = sum;
    __syncthreads();
    if (tid == 0) {
        float s2 = 0.f;
        for (int i = 0; i < 16; i++) s2 += scratch[i];
        scratch[21] = s2;
    }
    __syncthreads();
    float inv = 1.0f / scratch[21];
    __syncthreads();                           // everyone read scratch before keys overwrite
    #pragma unroll
    for (int s = 0; s < 8; s++) {
        int l = tid + s*1024;
        float sm = pv[s] * inv;
        sim[(size_t)b*L_ + l] = sm;
        keys[l] = ((unsigned long long)__float_as_uint(sm) << 32) | (unsigned)(0xFFFFFFFFu - l);
    }
    __syncthreads();
    for (int ksz = 2; ksz <= L_; ksz <<= 1) {
        for (int j = ksz >> 1; j > 0; j >>= 1) {
            #pragma unroll
            for (int s = 0; s < 8; s++) {
                int i = tid + s*1024;
                int ixj = i ^ j;
                if (ixj > i) {
                    unsigned long long a = keys[i], c = keys[ixj];
                    bool desc = ((i & ksz) == 0);
                    bool sw = desc ? (a < c) : (a > c);
                    if (sw) { keys[i] = c; keys[ixj] = a; }
                }
            }
            __syncthreads();
        }
    }
    for (int t = tid; t < KTOP; t += 1024)
        idxo[b*KTOP + t] = (int)(0xFFFFFFFFu - (unsigned)(keys[t] & 0xFFFFFFFFu));
}

// ---------------- y: tiled over 32 consecutive t with 51-row LDS window ----------------
// y[b,t,c] = conv_w[c] * sum_{j=0..19} cf[j][c] * xp[b, idx[t-j], c]   (taps j>t read zeros)
#define TT 32
__global__ __launch_bounds__(256) void y_kernel(const float* __restrict__ xp,
    const int* __restrict__ idx, const float* __restrict__ conv_w,
    const float* __restrict__ cf, float* __restrict__ y)
{
    __shared__ float rows[(TT + JT - 1) * C_];   // 51 rows x 1KB = 51KB
    const int b = blockIdx.y;
    const int t0 = blockIdx.x * TT;
    const int tid = threadIdx.x;
    const int c4 = (tid & 63) * 4;
    const int tg = tid >> 6;
    const int* idxb = idx + b*KTOP;

    for (int s = tid; s < (TT + JT - 1) * 64; s += 256) {
        int r = s >> 6, cq = (s & 63) * 4;
        int gi = t0 - (JT - 1) + r;
        float4 v = make_float4(0.f, 0.f, 0.f, 0.f);
        if (gi >= 0 && gi < KTOP) {
            int l = idxb[gi];
            v = *(const float4*)&xp[((size_t)b*L_ + l)*C_ + cq];
        }
        *(float4*)&rows[r*C_ + cq] = v;
    }
    float4 cfr[JT];
    #pragma unroll
    for (int j = 0; j < JT; j++) cfr[j] = *(const float4*)&cf[j*C_ + c4];
    float4 cw = *(const float4*)&conv_w[c4];
    __syncthreads();

    #pragma unroll
    for (int u = 0; u < TT/4; u++) {
        int tl = tg + u*4;
        int t = t0 + tl;
        if (t < KTOP) {
            float4 acc = make_float4(0.f, 0.f, 0.f, 0.f);
            #pragma unroll
            for (int j = 0; j < JT; j++) {
                const float4 v = *(const float4*)&rows[(tl + JT - 1 - j)*C_ + c4];
                acc.x = fmaf(cfr[j].x, v.x, acc.x);
                acc.y = fmaf(cfr[j].y, v.y, acc.y);
                acc.z = fmaf(cfr[j].z, v.z, acc.z);
                acc.w = fmaf(cfr[j].w, v.w, acc.w);
            }
            acc.x *= cw.x; acc.y *= cw.y; acc.z *= cw.z; acc.w *= cw.w;
            *(float4*)&y[((size_t)b*KTOP + t)*C_ + c4] = acc;
        }
    }
}

// ---------------- residual copy ----------------
__global__ void copy_kernel(const float4* __restrict__ src, float4* __restrict__ dst)
{
    size_t n4 = (size_t)M1*C_/4;
    for (size_t i = (size_t)blockIdx.x*blockDim.x + threadIdx.x; i < n4;
         i += (size_t)gridDim.x*blockDim.x)
        dst[i] = src[i];
}

// ---------------- GEMM2 + scatter epilogue: out[b,l,:] = x[b,l,:] + y@Wo.T + bo ----------------
__global__ __launch_bounds__(256, 2) void gemm2_kernel(
    const float* __restrict__ y, const float* __restrict__ WoT,
    const float* __restrict__ bo, const float* __restrict__ x,
    const int* __restrict__ idx, float* __restrict__ out0)
{
    __shared__ float As[32*132];
    __shared__ float Bs[32*256];
    const int tid = threadIdx.x;
    const int tn2 = tid & 31;
    const int tm2 = tid >> 5;
    const int m0 = blockIdx.x * 128;

    float acc[16][8];
    #pragma unroll
    for (int i = 0; i < 16; i++)
        #pragma unroll
        for (int j = 0; j < 8; j++) acc[i][j] = 0.f;

    for (int k0 = 0; k0 < C_; k0 += 32) {
        #pragma unroll
        for (int it = 0; it < 4; it++) {
            int idx2 = tid + it*256;
            int ar = idx2 >> 3;
            int ak = (idx2 & 7) * 4;
            int m = m0 + ar;
            float4 v = (m < M2) ? *(const float4*)&y[(size_t)m*C_ + k0 + ak]
                                : make_float4(0.f, 0.f, 0.f, 0.f);
            As[(ak+0)*132 + ar] = v.x;
            As[(ak+1)*132 + ar] = v.y;
            As[(ak+2)*132 + ar] = v.z;
            As[(ak+3)*132 + ar] = v.w;
        }
        #pragma unroll
        for (int it = 0; it < 8; it++) {
            int idx2 = tid + it*256;
            int br = idx2 >> 6;
            int bc = (idx2 & 63) * 4;
            *(float4*)&Bs[br*256 + bc] = *(const float4*)&WoT[(size_t)(k0 + br)*C_ + bc];
        }
        __syncthreads();
        #pragma unroll 2
        for (int kk = 0; kk < 32; kk++) {
            float a[16], b[8];
            *(float4*)&a[0]  = *(const float4*)&As[kk*132 + tm2*16];
            *(float4*)&a[4]  = *(const float4*)&As[kk*132 + tm2*16 + 4];
            *(float4*)&a[8]  = *(const float4*)&As[kk*132 + tm2*16 + 8];
            *(float4*)&a[12] = *(const float4*)&As[kk*132 + tm2*16 + 12];
            *(float4*)&b[0]  = *(const float4*)&Bs[kk*256 + tn2*8];
            *(float4*)&b[4]  = *(const float4*)&Bs[kk*256 + tn2*8 + 4];
            #pragma unroll
            for (int i = 0; i < 16; i++)
                #pragma unroll
                for (int j = 0; j < 8; j++)
                    acc[i][j] = fmaf(a[i], b[j], acc[i][j]);
        }
        __syncthreads();
    }
    float4 bo0 = *(const float4*)&bo[tn2*8];
    float4 bo1 = *(const float4*)&bo[tn2*8 + 4];
    #pragma unroll
    for (int i = 0; i < 16; i++) {
        int m = m0 + tm2*16 + i;
        if (m < M2) {
            int b = m / KTOP, t = m - b*KTOP;
            int l = idx[b*KTOP + t];
            size_t base = ((size_t)b*L_ + l)*C_;
            float4 x0 = *(const float4*)&x[base + tn2*8];
            float4 x1 = *(const float4*)&x[base + tn2*8 + 4];
            float4 o0 = make_float4(acc[i][0]+bo0.x+x0.x, acc[i][1]+bo0.y+x0.y,
                                    acc[i][2]+bo0.z+x0.z, acc[i][3]+bo0.w+x0.w);
            float4 o1 = make_float4(acc[i][4]+bo1.x+x1.x, acc[i][5]+bo1.y+x1.y,
                                    acc[i][6]+bo1.z+x1.z, acc[i][7]+bo1.w+x1.w);
            *(float4*)&out0[base + tn2*8]     = o0;
            *(float4*)&out0[base + tn2*8 + 4] = o1;
        }
    }
}

extern "C" void kernel_launch(void* const* d_in, const int* in_sizes, int n_in,
                              void* d_out, int out_size, void* d_ws, size_t ws_size,
                              hipStream_t stream)
{
    const float* x      = (const float*)d_in[0];
    const float* alpha  = (const float*)d_in[1];
    const float* dyt_w  = (const float*)d_in[2];
    const float* dyt_b  = (const float*)d_in[3];
    const float* Wi     = (const float*)d_in[4];
    const float* bi     = (const float*)d_in[5];
    const float* conv_w = (const float*)d_in[6];
    const float* A      = (const float*)d_in[7];
    const float* Bp     = (const float*)d_in[8];
    const float* Cp     = (const float*)d_in[9];
    const float* Wo     = (const float*)d_in[10];
    const float* bo     = (const float*)d_in[11];

    float* ws  = (float*)d_ws;
    float* xp  = ws + XP_OFF;
    float* yb  = ws + Y_OFF;
    float* e   = ws + E_OFF;
    float* cn  = ws + CN_OFF;
    float* cf  = ws + CF_OFF;
    int*   idx = (int*)(ws + IDX_OFF);
    float* WiT = ws + WIT_OFF;
    float* WoT = ws + WOT_OFF;

    float* out0 = (float*)d_out;
    float* sim  = out0 + (size_t)M1*C_;

    transpose_kernel<<<dim3(8,8,2), dim3(32,8), 0, stream>>>(Wi, Wo, WiT, WoT);
    coef_kernel<<<1, 256, 0, stream>>>(A, Bp, Cp, cf);
    gemm1_kernel<<<M1/128, 256, 0, stream>>>(x, WiT, bi, alpha, dyt_w, dyt_b, xp);
    center_kernel<<<B_, 64, 0, stream>>>(xp, cn);
    e_kernel<<<M1/4, 256, 0, stream>>>(xp, cn, e);
    softsort_kernel<<<B_, 1024, 0, stream>>>(e, sim, idx);
    y_kernel<<<dim3((KTOP + TT - 1)/TT, B_), 256, 0, stream>>>(xp, idx, conv_w, cf, yb);
    copy_kernel<<<2048, 256, 0, stream>>>((const float4*)x, (float4*)out0);
    gemm2_kernel<<<(M2 + 127)/128, 256, 0, stream>>>(yb, WoT, bo, x, idx, out0);
}